// Round 1
// baseline (1397.888 us; speedup 1.0000x reference)
//
#include <hip/hip_runtime.h>

#define BN 4
#define CC 256
#define DQ 32
#define HWD 32
#define NN 1024

// ---------------- downsample (exact bilinear, even factor s) ----------------
__global__ __launch_bounds__(256) void ds_kernel(const float* __restrict__ src,
                                                 float* __restrict__ dst,
                                                 int total, int inHW, int s) {
  int idx = blockIdx.x * 256 + threadIdx.x;
  if (idx >= total) return;
  int ox = idx & 31;
  int oy = (idx >> 5) & 31;
  int bc = idx >> 10;  // b*C + c
  int ih = oy * s + (s >> 1) - 1;
  int iw = ox * s + (s >> 1) - 1;
  const float* p = src + (size_t)bc * inHW * inHW;
  dst[idx] = 0.25f * (p[(size_t)ih * inHW + iw] + p[(size_t)ih * inHW + iw + 1] +
                      p[(size_t)(ih + 1) * inHW + iw] + p[(size_t)(ih + 1) * inHW + iw + 1]);
}

// ---------------- conv3x3 + BN(scale,bias) + ReLU, accumulate into multi ----
#define OCB 4
#define CHK 8
__global__ __launch_bounds__(256) void conv_kernel(
    const float* __restrict__ ds, const float* __restrict__ w,
    const float* __restrict__ sc, const float* __restrict__ bi,
    float* __restrict__ multi, int Cin, int first) {
  __shared__ float tile[CHK][34][35];
  int blk = blockIdx.x;
  int ocg = blk % (CC / OCB);
  int b = blk / (CC / OCB);
  int oc0 = ocg * OCB;
  int tid = threadIdx.x;
  int px = tid & 31;   // ox
  int py0 = tid >> 5;  // oy base; rows py0 + 8*p

  float acc[OCB][4];
#pragma unroll
  for (int o = 0; o < OCB; ++o)
#pragma unroll
    for (int p = 0; p < 4; ++p) acc[o][p] = 0.f;

  for (int c0 = 0; c0 < Cin; c0 += CHK) {
    // cooperative load CHK channels, 34x34 zero-padded window
    for (int e = tid; e < CHK * 34 * 34; e += 256) {
      int ch = e / (34 * 34);
      int rem = e % (34 * 34);
      int y = rem / 34, x = rem % 34;
      int iy = y - 1, ix = x - 1;
      float v = 0.f;
      if ((unsigned)iy < 32u && (unsigned)ix < 32u)
        v = ds[(((size_t)b * Cin + c0 + ch) * 32 + iy) * 32 + ix];
      tile[ch][y][x] = v;
    }
    __syncthreads();
#pragma unroll
    for (int ch = 0; ch < CHK; ++ch) {
      float wv[OCB][9];
#pragma unroll
      for (int o = 0; o < OCB; ++o)
#pragma unroll
        for (int k = 0; k < 9; ++k)
          wv[o][k] = w[((size_t)(oc0 + o) * Cin + c0 + ch) * 9 + k];  // uniform -> SGPR
#pragma unroll
      for (int p = 0; p < 4; ++p) {
        int oy = py0 + p * 8;
#pragma unroll
        for (int ky = 0; ky < 3; ++ky) {
          float v0 = tile[ch][oy + ky][px];
          float v1 = tile[ch][oy + ky][px + 1];
          float v2 = tile[ch][oy + ky][px + 2];
#pragma unroll
          for (int o = 0; o < OCB; ++o) {
            acc[o][p] = fmaf(wv[o][ky * 3 + 0], v0, acc[o][p]);
            acc[o][p] = fmaf(wv[o][ky * 3 + 1], v1, acc[o][p]);
            acc[o][p] = fmaf(wv[o][ky * 3 + 2], v2, acc[o][p]);
          }
        }
      }
    }
    __syncthreads();
  }
#pragma unroll
  for (int o = 0; o < OCB; ++o) {
    float s_ = sc[oc0 + o], b_ = bi[oc0 + o];
#pragma unroll
    for (int p = 0; p < 4; ++p) {
      int oy = py0 + p * 8;
      float r = fmaf(acc[o][p], s_, b_);
      r = r > 0.f ? r : 0.f;
      size_t off = (((size_t)b * CC + oc0 + o) * HWD + oy) * HWD + px;
      if (first) multi[off] = r;
      else multi[off] += r;
    }
  }
}

// ---------------- 1x1 conv (channel matmul), optional positional add --------
__global__ __launch_bounds__(256) void mm1x1_kernel(
    const float* __restrict__ in, const float* __restrict__ w,
    const float* __restrict__ bias, const float* __restrict__ relh,
    const float* __restrict__ relw, float* __restrict__ out,
    int Cin, int Cout) {
  int bidx = blockIdx.x;
  int nblk = bidx & 3;  // N/256 = 4
  bidx >>= 2;
  int ncog = Cout / 16;
  int cog = bidx % ncog;
  int b = bidx / ncog;
  int n = nblk * 256 + threadIdx.x;
  int co0 = cog * 16;
  float acc[16];
#pragma unroll
  for (int o = 0; o < 16; ++o) acc[o] = 0.f;
  const float* xin = in + (size_t)b * Cin * NN + n;
  for (int c = 0; c < Cin; ++c) {
    float xv = xin[(size_t)c * NN];
#pragma unroll
    for (int o = 0; o < 16; ++o)
      acc[o] = fmaf(w[(size_t)(co0 + o) * Cin + c], xv, acc[o]);  // uniform -> SGPR
  }
  int h = n >> 5, wp = n & 31;
#pragma unroll
  for (int o = 0; o < 16; ++o) {
    float r = acc[o] + bias[co0 + o];
    if (relh) r += relh[(co0 + o) * HWD + h] + relw[(co0 + o) * HWD + wp];
    out[((size_t)b * Cout + co0 + o) * NN + n] = r;
  }
}

// ---------------- energy = q·(k+pos), row softmax -> attn -------------------
__global__ __launch_bounds__(256) void attn_kernel(
    const float* __restrict__ q, const float* __restrict__ kp,
    float* __restrict__ attn) {
  __shared__ float qs[DQ][8];
  __shared__ float redm[4][8], reds[4][8];
  int bidx = blockIdx.x;
  int ig = bidx & 127;  // N/8 = 128 row-groups
  int b = bidx >> 7;
  int i0 = ig * 8;
  int tid = threadIdx.x;
  if (tid < DQ * 8) {
    int c = tid >> 3, r = tid & 7;
    qs[c][r] = q[((size_t)b * DQ + c) * NN + i0 + r];
  }
  __syncthreads();
  float e[8][4];
#pragma unroll
  for (int r = 0; r < 8; ++r)
#pragma unroll
    for (int k = 0; k < 4; ++k) e[r][k] = 0.f;
  const float* kpb = kp + (size_t)b * DQ * NN + tid;
  for (int c = 0; c < DQ; ++c) {
    float k0 = kpb[0], k1 = kpb[256], k2 = kpb[512], k3 = kpb[768];
    kpb += NN;
#pragma unroll
    for (int r = 0; r < 8; ++r) {
      float qv = qs[c][r];
      e[r][0] = fmaf(qv, k0, e[r][0]);
      e[r][1] = fmaf(qv, k1, e[r][1]);
      e[r][2] = fmaf(qv, k2, e[r][2]);
      e[r][3] = fmaf(qv, k3, e[r][3]);
    }
  }
  int lane = tid & 63, wvi = tid >> 6;
#pragma unroll
  for (int r = 0; r < 8; ++r) {
    float mm = fmaxf(fmaxf(e[r][0], e[r][1]), fmaxf(e[r][2], e[r][3]));
#pragma unroll
    for (int off = 32; off > 0; off >>= 1) mm = fmaxf(mm, __shfl_xor(mm, off));
    if (lane == 0) redm[wvi][r] = mm;
  }
  __syncthreads();
#pragma unroll
  for (int r = 0; r < 8; ++r) {
    float mm = fmaxf(fmaxf(redm[0][r], redm[1][r]), fmaxf(redm[2][r], redm[3][r]));
    float ss = 0.f;
#pragma unroll
    for (int k = 0; k < 4; ++k) {
      e[r][k] = __expf(e[r][k] - mm);
      ss += e[r][k];
    }
#pragma unroll
    for (int off = 32; off > 0; off >>= 1) ss += __shfl_xor(ss, off);
    if (lane == 0) reds[wvi][r] = ss;
  }
  __syncthreads();
#pragma unroll
  for (int r = 0; r < 8; ++r) {
    float inv = 1.f / (reds[0][r] + reds[1][r] + reds[2][r] + reds[3][r]);
    float* arow = attn + ((size_t)b * NN + i0 + r) * NN + tid;
    arow[0] = e[r][0] * inv;
    arow[256] = e[r][1] * inv;
    arow[512] = e[r][2] * inv;
    arow[768] = e[r][3] * inv;
  }
}

// ---------------- out[b,c,i] = gamma * sum_j v[b,c,j]*attn[b,i,j] + x -------
#define CT 64
#define IT 128
#define TJ 32
__global__ __launch_bounds__(256) void out_kernel(
    const float* __restrict__ v, const float* __restrict__ attn,
    const float* __restrict__ x, const float* __restrict__ gamma,
    float* __restrict__ out) {
  __shared__ float vt[CT][TJ + 1];
  __shared__ float at[IT][TJ + 1];
  int bidx = blockIdx.x;
  int ig = bidx % (NN / IT);
  bidx /= (NN / IT);
  int cg = bidx % (CC / CT);
  int b = bidx / (CC / CT);
  int c0 = cg * CT, i0 = ig * IT;
  int tid = threadIdx.x;
  int tc = (tid & 7) * 8;   // 8 c per thread
  int ti = (tid >> 3) * 4;  // 4 i per thread
  float acc[8][4];
#pragma unroll
  for (int ci = 0; ci < 8; ++ci)
#pragma unroll
    for (int ii = 0; ii < 4; ++ii) acc[ci][ii] = 0.f;

  for (int j0 = 0; j0 < NN; j0 += TJ) {
    for (int e = tid; e < CT * TJ; e += 256) {
      int c = e / TJ, j = e % TJ;
      vt[c][j] = v[((size_t)b * CC + c0 + c) * NN + j0 + j];
    }
    for (int e = tid; e < IT * TJ; e += 256) {
      int i = e / TJ, j = e % TJ;
      at[i][j] = attn[((size_t)b * NN + i0 + i) * NN + j0 + j];
    }
    __syncthreads();
#pragma unroll 4
    for (int j = 0; j < TJ; ++j) {
      float av[4], vv[8];
#pragma unroll
      for (int k = 0; k < 4; ++k) av[k] = at[ti + k][j];
#pragma unroll
      for (int k = 0; k < 8; ++k) vv[k] = vt[tc + k][j];
#pragma unroll
      for (int ci = 0; ci < 8; ++ci)
#pragma unroll
        for (int ii = 0; ii < 4; ++ii) acc[ci][ii] = fmaf(vv[ci], av[ii], acc[ci][ii]);
    }
    __syncthreads();
  }
  float g = gamma[0];
#pragma unroll
  for (int ci = 0; ci < 8; ++ci)
#pragma unroll
    for (int ii = 0; ii < 4; ++ii) {
      size_t off = ((size_t)b * CC + c0 + tc + ci) * NN + i0 + ti + ii;
      out[off] = fmaf(g, acc[ci][ii], x[off]);
    }
}

extern "C" void kernel_launch(void* const* d_in, const int* in_sizes, int n_in,
                              void* d_out, int out_size, void* d_ws, size_t ws_size,
                              hipStream_t stream) {
  const float* x    = (const float*)d_in[0];
  const float* x0   = (const float*)d_in[1];
  const float* x1   = (const float*)d_in[2];
  const float* x2   = (const float*)d_in[3];
  const float* x3   = (const float*)d_in[4];
  const float* w0   = (const float*)d_in[5];
  const float* s0   = (const float*)d_in[6];
  const float* b0   = (const float*)d_in[7];
  const float* w1   = (const float*)d_in[8];
  const float* s1   = (const float*)d_in[9];
  const float* b1   = (const float*)d_in[10];
  const float* w2   = (const float*)d_in[11];
  const float* s2   = (const float*)d_in[12];
  const float* b2   = (const float*)d_in[13];
  const float* w3   = (const float*)d_in[14];
  const float* s3   = (const float*)d_in[15];
  const float* b3   = (const float*)d_in[16];
  const float* qw   = (const float*)d_in[17];
  const float* qbi  = (const float*)d_in[18];
  const float* kw   = (const float*)d_in[19];
  const float* kbi  = (const float*)d_in[20];
  const float* vw   = (const float*)d_in[21];
  const float* vbi  = (const float*)d_in[22];
  const float* relh = (const float*)d_in[23];
  const float* relw = (const float*)d_in[24];
  const float* gamma= (const float*)d_in[25];

  float* ws    = (float*)d_ws;
  float* ds0   = ws;               // 131072
  float* ds1   = ds0 + 131072;     // 262144
  float* ds2   = ds1 + 262144;     // 524288
  float* ds3   = ds2 + 524288;     // 1048576
  float* multi = ds3 + 1048576;    // 1048576
  float* qbuf  = multi + 1048576;  // 131072
  float* kpbuf = qbuf + 131072;    // 131072
  float* vbuf  = kpbuf + 131072;   // 1048576

  float* out  = (float*)d_out;
  float* attn = out + (size_t)BN * CC * NN;

  ds_kernel<<<512, 256, 0, stream>>>(x0, ds0, 131072, 512, 16);
  ds_kernel<<<1024, 256, 0, stream>>>(x1, ds1, 262144, 256, 8);
  ds_kernel<<<2048, 256, 0, stream>>>(x2, ds2, 524288, 128, 4);
  ds_kernel<<<4096, 256, 0, stream>>>(x3, ds3, 1048576, 64, 2);

  conv_kernel<<<BN * (CC / OCB), 256, 0, stream>>>(ds0, w0, s0, b0, multi, 32, 1);
  conv_kernel<<<BN * (CC / OCB), 256, 0, stream>>>(ds1, w1, s1, b1, multi, 64, 0);
  conv_kernel<<<BN * (CC / OCB), 256, 0, stream>>>(ds2, w2, s2, b2, multi, 128, 0);
  conv_kernel<<<BN * (CC / OCB), 256, 0, stream>>>(ds3, w3, s3, b3, multi, 256, 0);

  mm1x1_kernel<<<BN * (DQ / 16) * 4, 256, 0, stream>>>(multi, qw, qbi, nullptr, nullptr, qbuf, CC, DQ);
  mm1x1_kernel<<<BN * (DQ / 16) * 4, 256, 0, stream>>>(x, kw, kbi, relh, relw, kpbuf, CC, DQ);
  mm1x1_kernel<<<BN * (CC / 16) * 4, 256, 0, stream>>>(x, vw, vbi, nullptr, nullptr, vbuf, CC, CC);

  attn_kernel<<<BN * 128, 256, 0, stream>>>(qbuf, kpbuf, attn);

  out_kernel<<<BN * (CC / CT) * (NN / IT), 256, 0, stream>>>(vbuf, attn, x, gamma, out);
}

// Round 2
// 618.703 us; speedup vs baseline: 2.2594x; 2.2594x over previous
//
#include <hip/hip_runtime.h>
#include <stdint.h>

#define BN 4
#define CC 256
#define DQ 32
#define HWD 32
#define NN 1024

typedef __attribute__((ext_vector_type(8))) short short8v;
typedef __attribute__((ext_vector_type(16))) float float16v;

__device__ __forceinline__ short f2bf(float f) {
  union { float f; uint32_t u; } v; v.f = f;
  uint32_t r = v.u + 0x7FFFu + ((v.u >> 16) & 1u);
  return (short)(r >> 16);
}

// ---------------- downsample (exact bilinear, even factor s) ----------------
__global__ __launch_bounds__(256) void ds_kernel(const float* __restrict__ src,
                                                 float* __restrict__ dst,
                                                 int total, int inHW, int s) {
  int idx = blockIdx.x * 256 + threadIdx.x;
  if (idx >= total) return;
  int ox = idx & 31;
  int oy = (idx >> 5) & 31;
  int bc = idx >> 10;  // b*C + c
  int ih = oy * s + (s >> 1) - 1;
  int iw = ox * s + (s >> 1) - 1;
  const float* p = src + (size_t)bc * inHW * inHW;
  dst[idx] = 0.25f * (p[(size_t)ih * inHW + iw] + p[(size_t)ih * inHW + iw + 1] +
                      p[(size_t)(ih + 1) * inHW + iw] + p[(size_t)(ih + 1) * inHW + iw + 1]);
}

// ---------------- weight repack: fragment-ordered bf16 ----------------------
// layout per scale region: [(ocg*chunks+chunk)][tap][lane][j]  (idx = g2*4608 + tap*512 + l*8 + j)
// oc = ocg*32 + (l&31);  c = chunk*16 + 8*(l>>5) + j
__global__ __launch_bounds__(256) void repack_kernel(const float* __restrict__ w,
                                                     short* __restrict__ wpk,
                                                     int Cin, int chunks, int total) {
  int idx = blockIdx.x * 256 + threadIdx.x;
  if (idx >= total) return;
  int g2 = idx / 4608;
  int rem = idx % 4608;
  int tap = rem >> 9;
  int l = (rem >> 3) & 63;
  int j = rem & 7;
  int ocg = g2 / chunks;
  int chunk = g2 % chunks;
  int oc = ocg * 32 + (l & 31);
  int c = chunk * 16 + ((l >> 5) << 3) + j;
  wpk[idx] = f2bf(w[((size_t)oc * Cin + c) * 9 + tap]);
}

// ---------------- fused 4-scale conv3x3 + BN + ReLU + sum via MFMA ----------
__global__ __launch_bounds__(256) void conv_mfma_kernel(
    const float* __restrict__ ds0, const float* __restrict__ ds1,
    const float* __restrict__ ds2, const float* __restrict__ ds3,
    const short* __restrict__ wpk,
    const float* __restrict__ sc0, const float* __restrict__ bi0,
    const float* __restrict__ sc1, const float* __restrict__ bi1,
    const float* __restrict__ sc2, const float* __restrict__ bi2,
    const float* __restrict__ sc3, const float* __restrict__ bi3,
    float* __restrict__ multi) {
  __shared__ __align__(16) short lds_x[2][6][34][8];  // [chH][row][col][chL] bf16
  int tid = threadIdx.x;
  int l = tid & 63;
  int wv = tid >> 6;  // wave id -> image row offset within the 4-row tile
  int bid = blockIdx.x;
  int rowq = bid & 7;
  int ocg = (bid >> 3) & 7;
  int b = bid >> 6;
  int oy0 = rowq * 4;
  int oc0 = ocg * 32;

  const float* dsv[4] = {ds0, ds1, ds2, ds3};
  const float* scv[4] = {sc0, sc1, sc2, sc3};
  const float* biv[4] = {bi0, bi1, bi2, bi3};
  const int cins[4] = {32, 64, 128, 256};
  const int wofs[4] = {0, 73728, 221184, 516096};

  float sum[16];
#pragma unroll
  for (int r = 0; r < 16; ++r) sum[r] = 0.f;

  int col = l & 31;
  int chH = l >> 5;

#pragma unroll
  for (int s = 0; s < 4; ++s) {
    int Cin = cins[s];
    int chunks = Cin >> 4;
    const float* img = dsv[s] + (size_t)b * Cin * 1024;
    const short* wbase = wpk + wofs[s] + (size_t)(ocg * chunks) * 4608;
    float16v acc;
#pragma unroll
    for (int r = 0; r < 16; ++r) acc[r] = 0.f;
    for (int ck = 0; ck < chunks; ++ck) {
      __syncthreads();
      // stage 16 channels x 6 rows x 34 cols (zero-padded), col-fastest (coalesced)
      for (int e = tid; e < 16 * 6 * 34; e += 256) {
        int ch = e / 204;
        int rem = e % 204;
        int row = rem / 34;
        int cx = rem % 34;
        int iy = oy0 - 1 + row;
        int ix = cx - 1;
        float v = 0.f;
        if ((unsigned)iy < 32u && (unsigned)ix < 32u)
          v = img[((size_t)(ck * 16 + ch) * 32 + iy) * 32 + ix];
        lds_x[ch >> 3][row][cx][ch & 7] = f2bf(v);
      }
      __syncthreads();
      const short8v* wf = (const short8v*)(wbase + (size_t)ck * 4608);
#pragma unroll
      for (int ky = 0; ky < 3; ++ky)
#pragma unroll
        for (int kx = 0; kx < 3; ++kx) {
          int tap = ky * 3 + kx;
          short8v av = wf[tap * 64 + l];
          short8v bv = *(const short8v*)&lds_x[chH][wv + ky][col + kx][0];
          acc = __builtin_amdgcn_mfma_f32_32x32x16_bf16(av, bv, acc, 0, 0, 0);
        }
    }
    const float* sc = scv[s];
    const float* bi = biv[s];
#pragma unroll
    for (int r = 0; r < 16; ++r) {
      int ocl = (r & 3) + ((r >> 2) << 3) + ((l >> 5) << 2);
      float t = fmaf(acc[r], sc[oc0 + ocl], bi[oc0 + ocl]);
      sum[r] += t > 0.f ? t : 0.f;
    }
  }
#pragma unroll
  for (int r = 0; r < 16; ++r) {
    int ocl = (r & 3) + ((r >> 2) << 3) + ((l >> 5) << 2);
    multi[(((size_t)b * CC + oc0 + ocl) * HWD + oy0 + wv) * HWD + col] = sum[r];
  }
}

// ---------------- 1x1 conv (channel matmul), optional positional add --------
__global__ __launch_bounds__(256) void mm1x1_kernel(
    const float* __restrict__ in, const float* __restrict__ w,
    const float* __restrict__ bias, const float* __restrict__ relh,
    const float* __restrict__ relw, float* __restrict__ out,
    int Cin, int Cout) {
  int bidx = blockIdx.x;
  int nblk = bidx & 3;  // N/256 = 4
  bidx >>= 2;
  int ncog = Cout / 16;
  int cog = bidx % ncog;
  int b = bidx / ncog;
  int n = nblk * 256 + threadIdx.x;
  int co0 = cog * 16;
  float acc[16];
#pragma unroll
  for (int o = 0; o < 16; ++o) acc[o] = 0.f;
  const float* xin = in + (size_t)b * Cin * NN + n;
  for (int c = 0; c < Cin; ++c) {
    float xv = xin[(size_t)c * NN];
#pragma unroll
    for (int o = 0; o < 16; ++o)
      acc[o] = fmaf(w[(size_t)(co0 + o) * Cin + c], xv, acc[o]);
  }
  int h = n >> 5, wp = n & 31;
#pragma unroll
  for (int o = 0; o < 16; ++o) {
    float r = acc[o] + bias[co0 + o];
    if (relh) r += relh[(co0 + o) * HWD + h] + relw[(co0 + o) * HWD + wp];
    out[((size_t)b * Cout + co0 + o) * NN + n] = r;
  }
}

// ---------------- energy = q·(k+pos), row softmax -> attn -------------------
__global__ __launch_bounds__(256) void attn_kernel(
    const float* __restrict__ q, const float* __restrict__ kp,
    float* __restrict__ attn) {
  __shared__ float qs[DQ][8];
  __shared__ float redm[4][8], reds[4][8];
  int bidx = blockIdx.x;
  int ig = bidx & 127;
  int b = bidx >> 7;
  int i0 = ig * 8;
  int tid = threadIdx.x;
  if (tid < DQ * 8) {
    int c = tid >> 3, r = tid & 7;
    qs[c][r] = q[((size_t)b * DQ + c) * NN + i0 + r];
  }
  __syncthreads();
  float e[8][4];
#pragma unroll
  for (int r = 0; r < 8; ++r)
#pragma unroll
    for (int k = 0; k < 4; ++k) e[r][k] = 0.f;
  const float* kpb = kp + (size_t)b * DQ * NN + tid;
  for (int c = 0; c < DQ; ++c) {
    float k0 = kpb[0], k1 = kpb[256], k2 = kpb[512], k3 = kpb[768];
    kpb += NN;
#pragma unroll
    for (int r = 0; r < 8; ++r) {
      float qv = qs[c][r];
      e[r][0] = fmaf(qv, k0, e[r][0]);
      e[r][1] = fmaf(qv, k1, e[r][1]);
      e[r][2] = fmaf(qv, k2, e[r][2]);
      e[r][3] = fmaf(qv, k3, e[r][3]);
    }
  }
  int lane = tid & 63, wvi = tid >> 6;
#pragma unroll
  for (int r = 0; r < 8; ++r) {
    float mm = fmaxf(fmaxf(e[r][0], e[r][1]), fmaxf(e[r][2], e[r][3]));
#pragma unroll
    for (int off = 32; off > 0; off >>= 1) mm = fmaxf(mm, __shfl_xor(mm, off));
    if (lane == 0) redm[wvi][r] = mm;
  }
  __syncthreads();
#pragma unroll
  for (int r = 0; r < 8; ++r) {
    float mm = fmaxf(fmaxf(redm[0][r], redm[1][r]), fmaxf(redm[2][r], redm[3][r]));
    float ss = 0.f;
#pragma unroll
    for (int k = 0; k < 4; ++k) {
      e[r][k] = __expf(e[r][k] - mm);
      ss += e[r][k];
    }
#pragma unroll
    for (int off = 32; off > 0; off >>= 1) ss += __shfl_xor(ss, off);
    if (lane == 0) reds[wvi][r] = ss;
  }
  __syncthreads();
#pragma unroll
  for (int r = 0; r < 8; ++r) {
    float inv = 1.f / (reds[0][r] + reds[1][r] + reds[2][r] + reds[3][r]);
    float* arow = attn + ((size_t)b * NN + i0 + r) * NN + tid;
    arow[0] = e[r][0] * inv;
    arow[256] = e[r][1] * inv;
    arow[512] = e[r][2] * inv;
    arow[768] = e[r][3] * inv;
  }
}

// ---------------- out[b,c,i] = gamma * sum_j v[b,c,j]*attn[b,i,j] + x -------
#define CT 64
#define IT 128
#define TJ 32
__global__ __launch_bounds__(256) void out_kernel(
    const float* __restrict__ v, const float* __restrict__ attn,
    const float* __restrict__ x, const float* __restrict__ gamma,
    float* __restrict__ out) {
  __shared__ float vt[CT][TJ + 1];
  __shared__ float at[IT][TJ + 1];
  int bidx = blockIdx.x;
  int ig = bidx % (NN / IT);
  bidx /= (NN / IT);
  int cg = bidx % (CC / CT);
  int b = bidx / (CC / CT);
  int c0 = cg * CT, i0 = ig * IT;
  int tid = threadIdx.x;
  int tc = (tid & 7) * 8;
  int ti = (tid >> 3) * 4;
  float acc[8][4];
#pragma unroll
  for (int ci = 0; ci < 8; ++ci)
#pragma unroll
    for (int ii = 0; ii < 4; ++ii) acc[ci][ii] = 0.f;

  for (int j0 = 0; j0 < NN; j0 += TJ) {
    for (int e = tid; e < CT * TJ; e += 256) {
      int c = e / TJ, j = e % TJ;
      vt[c][j] = v[((size_t)b * CC + c0 + c) * NN + j0 + j];
    }
    for (int e = tid; e < IT * TJ; e += 256) {
      int i = e / TJ, j = e % TJ;
      at[i][j] = attn[((size_t)b * NN + i0 + i) * NN + j0 + j];
    }
    __syncthreads();
#pragma unroll 4
    for (int j = 0; j < TJ; ++j) {
      float av[4], vvv[8];
#pragma unroll
      for (int k = 0; k < 4; ++k) av[k] = at[ti + k][j];
#pragma unroll
      for (int k = 0; k < 8; ++k) vvv[k] = vt[tc + k][j];
#pragma unroll
      for (int ci = 0; ci < 8; ++ci)
#pragma unroll
        for (int ii = 0; ii < 4; ++ii) acc[ci][ii] = fmaf(vvv[ci], av[ii], acc[ci][ii]);
    }
    __syncthreads();
  }
  float g = gamma[0];
#pragma unroll
  for (int ci = 0; ci < 8; ++ci)
#pragma unroll
    for (int ii = 0; ii < 4; ++ii) {
      size_t off = ((size_t)b * CC + c0 + tc + ci) * NN + i0 + ti + ii;
      out[off] = fmaf(g, acc[ci][ii], x[off]);
    }
}

extern "C" void kernel_launch(void* const* d_in, const int* in_sizes, int n_in,
                              void* d_out, int out_size, void* d_ws, size_t ws_size,
                              hipStream_t stream) {
  const float* x    = (const float*)d_in[0];
  const float* x0   = (const float*)d_in[1];
  const float* x1   = (const float*)d_in[2];
  const float* x2   = (const float*)d_in[3];
  const float* x3   = (const float*)d_in[4];
  const float* w0   = (const float*)d_in[5];
  const float* s0   = (const float*)d_in[6];
  const float* b0   = (const float*)d_in[7];
  const float* w1   = (const float*)d_in[8];
  const float* s1   = (const float*)d_in[9];
  const float* b1   = (const float*)d_in[10];
  const float* w2   = (const float*)d_in[11];
  const float* s2   = (const float*)d_in[12];
  const float* b2   = (const float*)d_in[13];
  const float* w3   = (const float*)d_in[14];
  const float* s3   = (const float*)d_in[15];
  const float* b3   = (const float*)d_in[16];
  const float* qw   = (const float*)d_in[17];
  const float* qbi  = (const float*)d_in[18];
  const float* kw   = (const float*)d_in[19];
  const float* kbi  = (const float*)d_in[20];
  const float* vw   = (const float*)d_in[21];
  const float* vbi  = (const float*)d_in[22];
  const float* relh = (const float*)d_in[23];
  const float* relw = (const float*)d_in[24];
  const float* gamma= (const float*)d_in[25];

  float* ws    = (float*)d_ws;
  float* ds0   = ws;               // 131072
  float* ds1   = ds0 + 131072;     // 262144
  float* ds2   = ds1 + 262144;     // 524288
  float* ds3   = ds2 + 524288;     // 1048576
  float* multi = ds3 + 1048576;    // 1048576
  float* qbuf  = multi + 1048576;  // 131072
  float* kpbuf = qbuf + 131072;    // 131072
  float* vbuf  = kpbuf + 131072;   // 1048576
  short* wpk   = (short*)(vbuf + 1048576);  // 1105920 bf16

  float* out  = (float*)d_out;
  float* attn = out + (size_t)BN * CC * NN;

  ds_kernel<<<512, 256, 0, stream>>>(x0, ds0, 131072, 512, 16);
  ds_kernel<<<1024, 256, 0, stream>>>(x1, ds1, 262144, 256, 8);
  ds_kernel<<<2048, 256, 0, stream>>>(x2, ds2, 524288, 128, 4);
  ds_kernel<<<4096, 256, 0, stream>>>(x3, ds3, 1048576, 64, 2);

  repack_kernel<<<(73728 + 255) / 256, 256, 0, stream>>>(w0, wpk, 32, 2, 73728);
  repack_kernel<<<(147456 + 255) / 256, 256, 0, stream>>>(w1, wpk + 73728, 64, 4, 147456);
  repack_kernel<<<(294912 + 255) / 256, 256, 0, stream>>>(w2, wpk + 221184, 128, 8, 294912);
  repack_kernel<<<(589824 + 255) / 256, 256, 0, stream>>>(w3, wpk + 516096, 256, 16, 589824);

  conv_mfma_kernel<<<256, 256, 0, stream>>>(ds0, ds1, ds2, ds3, wpk,
                                            s0, b0, s1, b1, s2, b2, s3, b3, multi);

  mm1x1_kernel<<<BN * (DQ / 16) * 4, 256, 0, stream>>>(multi, qw, qbi, nullptr, nullptr, qbuf, CC, DQ);
  mm1x1_kernel<<<BN * (DQ / 16) * 4, 256, 0, stream>>>(x, kw, kbi, relh, relw, kpbuf, CC, DQ);
  mm1x1_kernel<<<BN * (CC / 16) * 4, 256, 0, stream>>>(x, vw, vbi, nullptr, nullptr, vbuf, CC, CC);

  attn_kernel<<<BN * 128, 256, 0, stream>>>(qbuf, kpbuf, attn);

  out_kernel<<<BN * (CC / CT) * (NN / IT), 256, 0, stream>>>(vbuf, attn, x, gamma, out);
}

// Round 3
// 400.680 us; speedup vs baseline: 3.4888x; 1.5441x over previous
//
#include <hip/hip_runtime.h>
#include <stdint.h>

#define BN 4
#define CC 256
#define DQ 32
#define HWD 32
#define NN 1024

typedef __attribute__((ext_vector_type(8))) short short8v;
typedef __attribute__((ext_vector_type(16))) float float16v;

__device__ __forceinline__ short f2bf(float f) {
  union { float f; uint32_t u; } v; v.f = f;
  uint32_t r = v.u + 0x7FFFu + ((v.u >> 16) & 1u);
  return (short)(r >> 16);
}

// ---------------- downsample (exact bilinear, even factor s) ----------------
__global__ __launch_bounds__(256) void ds_kernel(const float* __restrict__ src,
                                                 float* __restrict__ dst,
                                                 int total, int inHW, int s) {
  int idx = blockIdx.x * 256 + threadIdx.x;
  if (idx >= total) return;
  int ox = idx & 31;
  int oy = (idx >> 5) & 31;
  int bc = idx >> 10;  // b*C + c
  int ih = oy * s + (s >> 1) - 1;
  int iw = ox * s + (s >> 1) - 1;
  const float* p = src + (size_t)bc * inHW * inHW;
  dst[idx] = 0.25f * (p[(size_t)ih * inHW + iw] + p[(size_t)ih * inHW + iw + 1] +
                      p[(size_t)(ih + 1) * inHW + iw] + p[(size_t)(ih + 1) * inHW + iw + 1]);
}

// ---------------- weight repack: fragment-ordered bf16 ----------------------
__global__ __launch_bounds__(256) void repack_kernel(const float* __restrict__ w,
                                                     short* __restrict__ wpk,
                                                     int Cin, int chunks, int total) {
  int idx = blockIdx.x * 256 + threadIdx.x;
  if (idx >= total) return;
  int g2 = idx / 4608;
  int rem = idx % 4608;
  int tap = rem >> 9;
  int l = (rem >> 3) & 63;
  int j = rem & 7;
  int ocg = g2 / chunks;
  int chunk = g2 % chunks;
  int oc = ocg * 32 + (l & 31);
  int c = chunk * 16 + ((l >> 5) << 3) + j;
  wpk[idx] = f2bf(w[((size_t)oc * Cin + c) * 9 + tap]);
}

// ---------------- fused 4-scale conv3x3 + BN + ReLU + sum via MFMA ----------
__global__ __launch_bounds__(256) void conv_mfma_kernel(
    const float* __restrict__ ds0, const float* __restrict__ ds1,
    const float* __restrict__ ds2, const float* __restrict__ ds3,
    const short* __restrict__ wpk,
    const float* __restrict__ sc0, const float* __restrict__ bi0,
    const float* __restrict__ sc1, const float* __restrict__ bi1,
    const float* __restrict__ sc2, const float* __restrict__ bi2,
    const float* __restrict__ sc3, const float* __restrict__ bi3,
    float* __restrict__ multi) {
  __shared__ __align__(16) short lds_x[2][6][34][8];  // [chH][row][col][chL] bf16
  int tid = threadIdx.x;
  int l = tid & 63;
  int wv = tid >> 6;
  int bid = blockIdx.x;
  int rowq = bid & 7;
  int ocg = (bid >> 3) & 7;
  int b = bid >> 6;
  int oy0 = rowq * 4;
  int oc0 = ocg * 32;

  const float* dsv[4] = {ds0, ds1, ds2, ds3};
  const float* scv[4] = {sc0, sc1, sc2, sc3};
  const float* biv[4] = {bi0, bi1, bi2, bi3};
  const int cins[4] = {32, 64, 128, 256};
  const int wofs[4] = {0, 73728, 221184, 516096};

  float sum[16];
#pragma unroll
  for (int r = 0; r < 16; ++r) sum[r] = 0.f;

  int col = l & 31;
  int chH = l >> 5;

#pragma unroll
  for (int s = 0; s < 4; ++s) {
    int Cin = cins[s];
    int chunks = Cin >> 4;
    const float* img = dsv[s] + (size_t)b * Cin * 1024;
    const short* wbase = wpk + wofs[s] + (size_t)(ocg * chunks) * 4608;
    float16v acc;
#pragma unroll
    for (int r = 0; r < 16; ++r) acc[r] = 0.f;
    for (int ck = 0; ck < chunks; ++ck) {
      __syncthreads();
      for (int e = tid; e < 16 * 6 * 34; e += 256) {
        int ch = e / 204;
        int rem = e % 204;
        int row = rem / 34;
        int cx = rem % 34;
        int iy = oy0 - 1 + row;
        int ix = cx - 1;
        float v = 0.f;
        if ((unsigned)iy < 32u && (unsigned)ix < 32u)
          v = img[((size_t)(ck * 16 + ch) * 32 + iy) * 32 + ix];
        lds_x[ch >> 3][row][cx][ch & 7] = f2bf(v);
      }
      __syncthreads();
      const short8v* wf = (const short8v*)(wbase + (size_t)ck * 4608);
#pragma unroll
      for (int ky = 0; ky < 3; ++ky)
#pragma unroll
        for (int kx = 0; kx < 3; ++kx) {
          int tap = ky * 3 + kx;
          short8v av = wf[tap * 64 + l];
          short8v bv = *(const short8v*)&lds_x[chH][wv + ky][col + kx][0];
          acc = __builtin_amdgcn_mfma_f32_32x32x16_bf16(av, bv, acc, 0, 0, 0);
        }
    }
    const float* sc = scv[s];
    const float* bi = biv[s];
#pragma unroll
    for (int r = 0; r < 16; ++r) {
      int ocl = (r & 3) + ((r >> 2) << 3) + ((l >> 5) << 2);
      float t = fmaf(acc[r], sc[oc0 + ocl], bi[oc0 + ocl]);
      sum[r] += t > 0.f ? t : 0.f;
    }
  }
#pragma unroll
  for (int r = 0; r < 16; ++r) {
    int ocl = (r & 3) + ((r >> 2) << 3) + ((l >> 5) << 2);
    multi[(((size_t)b * CC + oc0 + ocl) * HWD + oy0 + wv) * HWD + col] = sum[r];
  }
}

// ---------------- 1x1 conv (channel matmul); fp32 out or bf16 out -----------
__global__ __launch_bounds__(256) void mm1x1_kernel(
    const float* __restrict__ in, const float* __restrict__ w,
    const float* __restrict__ bias, const float* __restrict__ relh,
    const float* __restrict__ relw, float* __restrict__ out,
    short* __restrict__ outbf, int Cin, int Cout) {
  int bidx = blockIdx.x;
  int nblk = bidx & 3;
  bidx >>= 2;
  int ncog = Cout / 16;
  int cog = bidx % ncog;
  int b = bidx / ncog;
  int n = nblk * 256 + threadIdx.x;
  int co0 = cog * 16;
  float acc[16];
#pragma unroll
  for (int o = 0; o < 16; ++o) acc[o] = 0.f;
  const float* xin = in + (size_t)b * Cin * NN + n;
  for (int c = 0; c < Cin; ++c) {
    float xv = xin[(size_t)c * NN];
#pragma unroll
    for (int o = 0; o < 16; ++o)
      acc[o] = fmaf(w[(size_t)(co0 + o) * Cin + c], xv, acc[o]);
  }
  int h = n >> 5, wp = n & 31;
#pragma unroll
  for (int o = 0; o < 16; ++o) {
    float r = acc[o] + bias[co0 + o];
    if (relh) r += relh[(co0 + o) * HWD + h] + relw[(co0 + o) * HWD + wp];
    size_t off = ((size_t)b * Cout + co0 + o) * NN + n;
    if (outbf) outbf[off] = f2bf(r);
    else out[off] = r;
  }
}

// ---------------- energy = q·(k+pos), row softmax -> attn (+bf16 copy) ------
__global__ __launch_bounds__(256) void attn_kernel(
    const float* __restrict__ q, const float* __restrict__ kp,
    float* __restrict__ attn, short* __restrict__ abf) {
  __shared__ float qs[DQ][8];
  __shared__ float redm[4][8], reds[4][8];
  int bidx = blockIdx.x;
  int ig = bidx & 127;
  int b = bidx >> 7;
  int i0 = ig * 8;
  int tid = threadIdx.x;
  if (tid < DQ * 8) {
    int c = tid >> 3, r = tid & 7;
    qs[c][r] = q[((size_t)b * DQ + c) * NN + i0 + r];
  }
  __syncthreads();
  float e[8][4];
#pragma unroll
  for (int r = 0; r < 8; ++r)
#pragma unroll
    for (int k = 0; k < 4; ++k) e[r][k] = 0.f;
  const float* kpb = kp + (size_t)b * DQ * NN + tid;
  for (int c = 0; c < DQ; ++c) {
    float k0 = kpb[0], k1 = kpb[256], k2 = kpb[512], k3 = kpb[768];
    kpb += NN;
#pragma unroll
    for (int r = 0; r < 8; ++r) {
      float qv = qs[c][r];
      e[r][0] = fmaf(qv, k0, e[r][0]);
      e[r][1] = fmaf(qv, k1, e[r][1]);
      e[r][2] = fmaf(qv, k2, e[r][2]);
      e[r][3] = fmaf(qv, k3, e[r][3]);
    }
  }
  int lane = tid & 63, wvi = tid >> 6;
#pragma unroll
  for (int r = 0; r < 8; ++r) {
    float mm = fmaxf(fmaxf(e[r][0], e[r][1]), fmaxf(e[r][2], e[r][3]));
#pragma unroll
    for (int off = 32; off > 0; off >>= 1) mm = fmaxf(mm, __shfl_xor(mm, off));
    if (lane == 0) redm[wvi][r] = mm;
  }
  __syncthreads();
#pragma unroll
  for (int r = 0; r < 8; ++r) {
    float mm = fmaxf(fmaxf(redm[0][r], redm[1][r]), fmaxf(redm[2][r], redm[3][r]));
    float ss = 0.f;
#pragma unroll
    for (int k = 0; k < 4; ++k) {
      e[r][k] = __expf(e[r][k] - mm);
      ss += e[r][k];
    }
#pragma unroll
    for (int off = 32; off > 0; off >>= 1) ss += __shfl_xor(ss, off);
    if (lane == 0) reds[wvi][r] = ss;
  }
  __syncthreads();
#pragma unroll
  for (int r = 0; r < 8; ++r) {
    float inv = 1.f / (reds[0][r] + reds[1][r] + reds[2][r] + reds[3][r]);
    size_t base = ((size_t)b * NN + i0 + r) * NN + tid;
    float a0 = e[r][0] * inv, a1 = e[r][1] * inv, a2 = e[r][2] * inv, a3 = e[r][3] * inv;
    attn[base] = a0; attn[base + 256] = a1; attn[base + 512] = a2; attn[base + 768] = a3;
    abf[base] = f2bf(a0); abf[base + 256] = f2bf(a1);
    abf[base + 512] = f2bf(a2); abf[base + 768] = f2bf(a3);
  }
}

// ---------------- out = gamma * V(bf16) . attn(bf16)^T + x  via MFMA --------
__global__ __launch_bounds__(256) void out_mfma_kernel(
    const short* __restrict__ vbf, const short* __restrict__ abf,
    const float* __restrict__ x, const float* __restrict__ gamma,
    float* __restrict__ out) {
  int tid = threadIdx.x;
  int l = tid & 63;
  int wv = tid >> 6;       // 2x2 waves
  int wc = wv >> 1, wi = wv & 1;
  int bid = blockIdx.x;
  int ig = bid & 15;       // 16 i-groups of 64
  int cg = (bid >> 4) & 3; // 4 c-groups of 64
  int b = bid >> 6;
  int c0 = cg * 64 + wc * 32;
  int i0 = ig * 64 + wi * 32;

  const short* vrow = vbf + ((size_t)b * CC + c0 + (l & 31)) * NN + ((l >> 5) << 3);
  const short* arow = abf + ((size_t)b * NN + i0 + (l & 31)) * NN + ((l >> 5) << 3);

  float16v acc;
#pragma unroll
  for (int r = 0; r < 16; ++r) acc[r] = 0.f;

#pragma unroll 4
  for (int j0 = 0; j0 < NN; j0 += 16) {
    short8v av = *(const short8v*)(vrow + j0);
    short8v bv = *(const short8v*)(arow + j0);
    acc = __builtin_amdgcn_mfma_f32_32x32x16_bf16(av, bv, acc, 0, 0, 0);
  }

  float g = gamma[0];
  int i = i0 + (l & 31);
#pragma unroll
  for (int r = 0; r < 16; ++r) {
    int c = c0 + (r & 3) + ((r >> 2) << 3) + ((l >> 5) << 2);
    size_t off = ((size_t)b * CC + c) * NN + i;
    out[off] = fmaf(g, acc[r], x[off]);
  }
}

extern "C" void kernel_launch(void* const* d_in, const int* in_sizes, int n_in,
                              void* d_out, int out_size, void* d_ws, size_t ws_size,
                              hipStream_t stream) {
  const float* x    = (const float*)d_in[0];
  const float* x0   = (const float*)d_in[1];
  const float* x1   = (const float*)d_in[2];
  const float* x2   = (const float*)d_in[3];
  const float* x3   = (const float*)d_in[4];
  const float* w0   = (const float*)d_in[5];
  const float* s0   = (const float*)d_in[6];
  const float* b0   = (const float*)d_in[7];
  const float* w1   = (const float*)d_in[8];
  const float* s1   = (const float*)d_in[9];
  const float* b1   = (const float*)d_in[10];
  const float* w2   = (const float*)d_in[11];
  const float* s2   = (const float*)d_in[12];
  const float* b2   = (const float*)d_in[13];
  const float* w3   = (const float*)d_in[14];
  const float* s3   = (const float*)d_in[15];
  const float* b3   = (const float*)d_in[16];
  const float* qw   = (const float*)d_in[17];
  const float* qbi  = (const float*)d_in[18];
  const float* kw   = (const float*)d_in[19];
  const float* kbi  = (const float*)d_in[20];
  const float* vw   = (const float*)d_in[21];
  const float* vbi  = (const float*)d_in[22];
  const float* relh = (const float*)d_in[23];
  const float* relw = (const float*)d_in[24];
  const float* gamma= (const float*)d_in[25];

  float* ws    = (float*)d_ws;
  float* ds0   = ws;               // 131072 f
  float* ds1   = ds0 + 131072;     // 262144 f
  float* ds2   = ds1 + 262144;     // 524288 f
  float* ds3   = ds2 + 524288;     // 1048576 f
  float* multi = ds3 + 1048576;    // 1048576 f
  float* qbuf  = multi + 1048576;  // 131072 f
  float* kpbuf = qbuf + 131072;    // 131072 f
  short* vbf   = (short*)(kpbuf + 131072);          // 1048576 bf16 (old vbuf slot)
  short* wpk   = (short*)(kpbuf + 131072 + 1048576); // 1105920 bf16
  // bf16 attn overlays the (dead-by-then) ds0..multi region: 4M shorts = 8 MB <= 12 MB
  short* abf   = (short*)ws;

  float* out  = (float*)d_out;
  float* attn = out + (size_t)BN * CC * NN;

  ds_kernel<<<512, 256, 0, stream>>>(x0, ds0, 131072, 512, 16);
  ds_kernel<<<1024, 256, 0, stream>>>(x1, ds1, 262144, 256, 8);
  ds_kernel<<<2048, 256, 0, stream>>>(x2, ds2, 524288, 128, 4);
  ds_kernel<<<4096, 256, 0, stream>>>(x3, ds3, 1048576, 64, 2);

  repack_kernel<<<(73728 + 255) / 256, 256, 0, stream>>>(w0, wpk, 32, 2, 73728);
  repack_kernel<<<(147456 + 255) / 256, 256, 0, stream>>>(w1, wpk + 73728, 64, 4, 147456);
  repack_kernel<<<(294912 + 255) / 256, 256, 0, stream>>>(w2, wpk + 221184, 128, 8, 294912);
  repack_kernel<<<(589824 + 255) / 256, 256, 0, stream>>>(w3, wpk + 516096, 256, 16, 589824);

  conv_mfma_kernel<<<256, 256, 0, stream>>>(ds0, ds1, ds2, ds3, wpk,
                                            s0, b0, s1, b1, s2, b2, s3, b3, multi);

  mm1x1_kernel<<<BN * (DQ / 16) * 4, 256, 0, stream>>>(multi, qw, qbi, nullptr, nullptr, qbuf, nullptr, CC, DQ);
  mm1x1_kernel<<<BN * (DQ / 16) * 4, 256, 0, stream>>>(x, kw, kbi, relh, relw, kpbuf, nullptr, CC, DQ);
  mm1x1_kernel<<<BN * (CC / 16) * 4, 256, 0, stream>>>(x, vw, vbi, nullptr, nullptr, nullptr, vbf, CC, CC);

  // attn: fp32 -> d_out, bf16 copy -> ws (ds/multi region is dead by now)
  attn_kernel<<<BN * 128, 256, 0, stream>>>(qbuf, kpbuf, attn, abf);

  out_mfma_kernel<<<BN * 4 * 16, 256, 0, stream>>>(vbf, abf, x, gamma, (float*)d_out);
}

// Round 5
// 189.335 us; speedup vs baseline: 7.3832x; 2.1163x over previous
//
#include <hip/hip_runtime.h>
#include <stdint.h>

#define BN 4
#define CC 256
#define DQ 32
#define HWD 32
#define NN 1024

typedef __attribute__((ext_vector_type(8))) short short8v;
typedef __attribute__((ext_vector_type(16))) float float16v;

__device__ __forceinline__ short f2bf(float f) {
  union { float f; uint32_t u; } v; v.f = f;
  uint32_t r = v.u + 0x7FFFu + ((v.u >> 16) & 1u);
  return (short)(r >> 16);
}

// ---- fused downsample + pad + bf16 convert:  pim[b][g][34][34][8] ----------
// g in [0,60): s0 g0..3, s1 g4..11, s2 g12..27, s3 g28..59 (8 channels each)
__global__ __launch_bounds__(256) void pad_kernel(
    const float* __restrict__ x0, const float* __restrict__ x1,
    const float* __restrict__ x2, const float* __restrict__ x3,
    short* __restrict__ pim) {
  int plane = blockIdx.y;  // b*60+g
  int idx = blockIdx.x * 256 + threadIdx.x;
  if (idx >= 9248) return;
  int b = plane / 60, g = plane % 60;
  int pr = idx / 272;
  int rem = idx % 272;
  int pc = rem >> 3, j = rem & 7;
  const float* xs;
  int s, gb, C;
  if (g < 4)       { xs = x0; s = 16; gb = 0;  C = 32; }
  else if (g < 12) { xs = x1; s = 8;  gb = 4;  C = 64; }
  else if (g < 28) { xs = x2; s = 4;  gb = 12; C = 128; }
  else             { xs = x3; s = 2;  gb = 28; C = 256; }
  float v = 0.f;
  if (pr >= 1 && pr <= 32 && pc >= 1 && pc <= 32) {
    int c = (g - gb) * 8 + j;
    int inHW = 32 * s;
    int ih = (pr - 1) * s + (s >> 1) - 1;
    int iw = (pc - 1) * s + (s >> 1) - 1;
    const float* p = xs + ((size_t)(b * C + c) * inHW + ih) * inHW + iw;
    v = 0.25f * (p[0] + p[1] + p[inHW] + p[inHW + 1]);
  }
  pim[(size_t)plane * 9248 + idx] = f2bf(v);
}

// ---------------- weight repack 3x3: fragment-ordered bf16 ------------------
__global__ __launch_bounds__(256) void repack_kernel(const float* __restrict__ w,
                                                     short* __restrict__ wpk,
                                                     int Cin, int chunks, int total) {
  int idx = blockIdx.x * 256 + threadIdx.x;
  if (idx >= total) return;
  int g2 = idx / 4608;
  int rem = idx % 4608;
  int tap = rem >> 9;
  int l = (rem >> 3) & 63;
  int j = rem & 7;
  int ocg = g2 / chunks;
  int chunk = g2 % chunks;
  int oc = ocg * 32 + (l & 31);
  int c = chunk * 16 + ((l >> 5) << 3) + j;
  wpk[idx] = f2bf(w[((size_t)oc * Cin + c) * 9 + tap]);
}

// ---------------- weight repack 1x1 -----------------------------------------
__global__ __launch_bounds__(256) void repack1x1_kernel(const float* __restrict__ w,
                                                        short* __restrict__ out,
                                                        int Cin, int total) {
  int idx = blockIdx.x * 256 + threadIdx.x;
  if (idx >= total) return;
  int j = idx & 7;
  int l = (idx >> 3) & 63;
  int g2 = idx >> 9;
  int chk = Cin >> 4;
  int ocg = g2 / chk, ck = g2 % chk;
  int oc = ocg * 32 + (l & 31);
  int c = ck * 16 + ((l >> 5) << 3) + j;
  out[idx] = f2bf(w[(size_t)oc * Cin + c]);
}

// ---------------- fused 4-scale conv3x3+BN+ReLU+sum, no-LDS MFMA ------------
__global__ __launch_bounds__(64) void conv_mfma2_kernel(
    const short* __restrict__ pim, const short* __restrict__ wpk,
    const float* __restrict__ sc0, const float* __restrict__ bi0,
    const float* __restrict__ sc1, const float* __restrict__ bi1,
    const float* __restrict__ sc2, const float* __restrict__ bi2,
    const float* __restrict__ sc3, const float* __restrict__ bi3,
    float* __restrict__ multi) {
  int l = threadIdx.x;
  int bid = blockIdx.x;
  int row = bid & 31;
  int ocg = (bid >> 5) & 7;
  int b = bid >> 8;
  int col = l & 31, chH = l >> 5;
  int oc0 = ocg * 32;

  const float* scv[4] = {sc0, sc1, sc2, sc3};
  const float* biv[4] = {bi0, bi1, bi2, bi3};
  const int cins[4] = {32, 64, 128, 256};
  const int gbase[4] = {0, 4, 12, 28};
  const int wofs[4] = {0, 73728, 221184, 516096};

  float sum[16];
#pragma unroll
  for (int r = 0; r < 16; ++r) sum[r] = 0.f;

#pragma unroll
  for (int s = 0; s < 4; ++s) {
    int chunks = cins[s] >> 4;
    const short* ap = wpk + wofs[s] + (size_t)(ocg * chunks) * 4608 + l * 8;
    const short* bp = pim + ((size_t)(b * 60 + gbase[s] + chH) * 1156 + row * 34 + col) * 8;
    float16v acc;
#pragma unroll
    for (int r = 0; r < 16; ++r) acc[r] = 0.f;
    for (int ck = 0; ck < chunks; ++ck) {
#pragma unroll
      for (int ky = 0; ky < 3; ++ky)
#pragma unroll
        for (int kx = 0; kx < 3; ++kx) {
          short8v av = *(const short8v*)(ap + (ky * 3 + kx) * 512);
          short8v bv = *(const short8v*)(bp + (ky * 34 + kx) * 8);
          acc = __builtin_amdgcn_mfma_f32_32x32x16_bf16(av, bv, acc, 0, 0, 0);
        }
      ap += 4608;
      bp += 2 * 1156 * 8;  // advance 2 channel-groups
    }
    const float* sc = scv[s];
    const float* bi = biv[s];
#pragma unroll
    for (int r = 0; r < 16; ++r) {
      int ocl = (r & 3) + ((r >> 2) << 3) + (chH << 2);
      float t = fmaf(acc[r], sc[oc0 + ocl], bi[oc0 + ocl]);
      sum[r] += t > 0.f ? t : 0.f;
    }
  }
#pragma unroll
  for (int r = 0; r < 16; ++r) {
    int ocl = (r & 3) + ((r >> 2) << 3) + (chH << 2);
    multi[((size_t)(b * CC + oc0 + ocl) * 32 + row) * 32 + col] = sum[r];
  }
}

// ---------------- transpose-convert x -> xT bf16 [b][n][c] ------------------
__global__ __launch_bounds__(256) void xT_kernel(const float* __restrict__ x,
                                                 short* __restrict__ xT) {
  __shared__ float t[32][33];
  int bid = blockIdx.x;
  int nb = bid & 31;
  int cb = (bid >> 5) & 7;
  int b = bid >> 8;
  int n0 = nb * 32, c0 = cb * 32;
  int tid = threadIdx.x;
  int a = tid >> 5, e = tid & 31;
#pragma unroll
  for (int k = 0; k < 4; ++k)
    t[a + 8 * k][e] = x[((size_t)(b * CC + c0 + a + 8 * k) * NN) + n0 + e];
  __syncthreads();
#pragma unroll
  for (int k = 0; k < 4; ++k)
    xT[((size_t)(b * NN + n0 + a + 8 * k) * CC) + c0 + e] = f2bf(t[e][a + 8 * k]);
}

// ---------------- 1x1 projection via MFMA (k with pos, v to bf16) -----------
__global__ __launch_bounds__(64) void proj1x1_kernel(
    const short* __restrict__ apk, const short* __restrict__ xT,
    const float* __restrict__ bias, const float* __restrict__ relh,
    const float* __restrict__ relw, float* __restrict__ outf,
    short* __restrict__ outbf, int nocg, int Cout) {
  int l = threadIdx.x;
  int bid = blockIdx.x;
  int nt = bid & 31;
  int rest = bid >> 5;
  int ocg = rest % nocg;
  int b = rest / nocg;
  int n = nt * 32 + (l & 31);
  const short* bp = xT + ((size_t)(b * NN) + n) * CC + ((l >> 5) << 3);
  const short* ap = apk + (size_t)ocg * 16 * 512 + l * 8;
  float16v acc;
#pragma unroll
  for (int r = 0; r < 16; ++r) acc[r] = 0.f;
#pragma unroll
  for (int ck = 0; ck < 16; ++ck) {
    short8v av = *(const short8v*)(ap + ck * 512);
    short8v bv = *(const short8v*)(bp + ck * 16);
    acc = __builtin_amdgcn_mfma_f32_32x32x16_bf16(av, bv, acc, 0, 0, 0);
  }
#pragma unroll
  for (int r = 0; r < 16; ++r) {
    int oc = ocg * 32 + (r & 3) + ((r >> 2) << 3) + ((l >> 5) << 2);
    float t = acc[r] + bias[oc];
    if (relh) t += relh[oc * 32 + (n >> 5)] + relw[oc * 32 + (n & 31)];
    size_t off = ((size_t)b * Cout + oc) * NN + n;
    if (outbf) outbf[off] = f2bf(t);
    else outf[off] = t;
  }
}

// ---------------- 1x1 conv fp32 (q only; reads fp32 multi) ------------------
__global__ __launch_bounds__(256) void mm1x1_kernel(
    const float* __restrict__ in, const float* __restrict__ w,
    const float* __restrict__ bias, float* __restrict__ out,
    int Cin, int Cout) {
  int bidx = blockIdx.x;
  int nblk = bidx & 3;
  bidx >>= 2;
  int ncog = Cout / 16;
  int cog = bidx % ncog;
  int b = bidx / ncog;
  int n = nblk * 256 + threadIdx.x;
  int co0 = cog * 16;
  float acc[16];
#pragma unroll
  for (int o = 0; o < 16; ++o) acc[o] = 0.f;
  const float* xin = in + (size_t)b * Cin * NN + n;
  for (int c = 0; c < Cin; ++c) {
    float xv = xin[(size_t)c * NN];
#pragma unroll
    for (int o = 0; o < 16; ++o)
      acc[o] = fmaf(w[(size_t)(co0 + o) * Cin + c], xv, acc[o]);
  }
#pragma unroll
  for (int o = 0; o < 16; ++o)
    out[((size_t)b * Cout + co0 + o) * NN + n] = acc[o] + bias[co0 + o];
}

// ---------------- energy = q·(k+pos), row softmax -> attn (+bf16 copy) ------
__global__ __launch_bounds__(256) void attn_kernel(
    const float* __restrict__ q, const float* __restrict__ kp,
    float* __restrict__ attn, short* __restrict__ abf) {
  __shared__ float qs[DQ][8];
  __shared__ float redm[4][8], reds[4][8];
  int bidx = blockIdx.x;
  int ig = bidx & 127;
  int b = bidx >> 7;
  int i0 = ig * 8;
  int tid = threadIdx.x;
  if (tid < DQ * 8) {
    int c = tid >> 3, r = tid & 7;
    qs[c][r] = q[((size_t)b * DQ + c) * NN + i0 + r];
  }
  __syncthreads();
  float e[8][4];
#pragma unroll
  for (int r = 0; r < 8; ++r)
#pragma unroll
    for (int k = 0; k < 4; ++k) e[r][k] = 0.f;
  const float* kpb = kp + (size_t)b * DQ * NN + tid;
  for (int c = 0; c < DQ; ++c) {
    float k0 = kpb[0], k1 = kpb[256], k2 = kpb[512], k3 = kpb[768];
    kpb += NN;
#pragma unroll
    for (int r = 0; r < 8; ++r) {
      float qv = qs[c][r];
      e[r][0] = fmaf(qv, k0, e[r][0]);
      e[r][1] = fmaf(qv, k1, e[r][1]);
      e[r][2] = fmaf(qv, k2, e[r][2]);
      e[r][3] = fmaf(qv, k3, e[r][3]);
    }
  }
  int lane = tid & 63, wvi = tid >> 6;
#pragma unroll
  for (int r = 0; r < 8; ++r) {
    float mm = fmaxf(fmaxf(e[r][0], e[r][1]), fmaxf(e[r][2], e[r][3]));
#pragma unroll
    for (int off = 32; off > 0; off >>= 1) mm = fmaxf(mm, __shfl_xor(mm, off));
    if (lane == 0) redm[wvi][r] = mm;
  }
  __syncthreads();
#pragma unroll
  for (int r = 0; r < 8; ++r) {
    float mm = fmaxf(fmaxf(redm[0][r], redm[1][r]), fmaxf(redm[2][r], redm[3][r]));
    float ss = 0.f;
#pragma unroll
    for (int k = 0; k < 4; ++k) {
      e[r][k] = __expf(e[r][k] - mm);
      ss += e[r][k];
    }
#pragma unroll
    for (int off = 32; off > 0; off >>= 1) ss += __shfl_xor(ss, off);
    if (lane == 0) reds[wvi][r] = ss;
  }
  __syncthreads();
#pragma unroll
  for (int r = 0; r < 8; ++r) {
    float inv = 1.f / (reds[0][r] + reds[1][r] + reds[2][r] + reds[3][r]);
    size_t base = ((size_t)b * NN + i0 + r) * NN + tid;
    float a0 = e[r][0] * inv, a1 = e[r][1] * inv, a2 = e[r][2] * inv, a3 = e[r][3] * inv;
    attn[base] = a0; attn[base + 256] = a1; attn[base + 512] = a2; attn[base + 768] = a3;
    abf[base] = f2bf(a0); abf[base + 256] = f2bf(a1);
    abf[base + 512] = f2bf(a2); abf[base + 768] = f2bf(a3);
  }
}

// ---------------- out = gamma * V(bf16) . attn(bf16)^T + x  via MFMA --------
__global__ __launch_bounds__(256) void out_mfma_kernel(
    const short* __restrict__ vbf, const short* __restrict__ abf,
    const float* __restrict__ x, const float* __restrict__ gamma,
    float* __restrict__ out) {
  int tid = threadIdx.x;
  int l = tid & 63;
  int wv = tid >> 6;
  int wc = wv >> 1, wi = wv & 1;
  int bid = blockIdx.x;
  int ig = bid & 15;
  int cg = (bid >> 4) & 3;
  int b = bid >> 6;
  int c0 = cg * 64 + wc * 32;
  int i0 = ig * 64 + wi * 32;

  const short* vrow = vbf + ((size_t)b * CC + c0 + (l & 31)) * NN + ((l >> 5) << 3);
  const short* arow = abf + ((size_t)b * NN + i0 + (l & 31)) * NN + ((l >> 5) << 3);

  float16v acc;
#pragma unroll
  for (int r = 0; r < 16; ++r) acc[r] = 0.f;

#pragma unroll 4
  for (int j0 = 0; j0 < NN; j0 += 16) {
    short8v av = *(const short8v*)(vrow + j0);
    short8v bv = *(const short8v*)(arow + j0);
    acc = __builtin_amdgcn_mfma_f32_32x32x16_bf16(av, bv, acc, 0, 0, 0);
  }

  float g = gamma[0];
  int i = i0 + (l & 31);
#pragma unroll
  for (int r = 0; r < 16; ++r) {
    int c = c0 + (r & 3) + ((r >> 2) << 3) + ((l >> 5) << 2);
    size_t off = ((size_t)b * CC + c) * NN + i;
    out[off] = fmaf(g, acc[r], x[off]);
  }
}

extern "C" void kernel_launch(void* const* d_in, const int* in_sizes, int n_in,
                              void* d_out, int out_size, void* d_ws, size_t ws_size,
                              hipStream_t stream) {
  const float* x    = (const float*)d_in[0];
  const float* x0   = (const float*)d_in[1];
  const float* x1   = (const float*)d_in[2];
  const float* x2   = (const float*)d_in[3];
  const float* x3   = (const float*)d_in[4];
  const float* w0   = (const float*)d_in[5];
  const float* s0   = (const float*)d_in[6];
  const float* b0   = (const float*)d_in[7];
  const float* w1   = (const float*)d_in[8];
  const float* s1   = (const float*)d_in[9];
  const float* b1   = (const float*)d_in[10];
  const float* w2   = (const float*)d_in[11];
  const float* s2   = (const float*)d_in[12];
  const float* b2   = (const float*)d_in[13];
  const float* w3   = (const float*)d_in[14];
  const float* s3   = (const float*)d_in[15];
  const float* b3   = (const float*)d_in[16];
  const float* qw   = (const float*)d_in[17];
  const float* qbi  = (const float*)d_in[18];
  const float* kw   = (const float*)d_in[19];
  const float* kbi  = (const float*)d_in[20];
  const float* vw   = (const float*)d_in[21];
  const float* vbi  = (const float*)d_in[22];
  const float* relh = (const float*)d_in[23];
  const float* relw = (const float*)d_in[24];
  const float* gamma= (const float*)d_in[25];

  float* ws = (float*)d_ws;
  short* pim   = (short*)ws;                       // 2,219,520 sh = 1,109,760 f
  float* multi = ws + 1109760;                     // 1,048,576 f
  float* qbuf  = ws + 2158336;                     // 131,072 f
  float* kpbuf = ws + 2289408;                     // 131,072 f
  short* xT    = (short*)(ws + 2420480);           // 1,048,576 sh
  short* vbf   = (short*)(ws + 2944768);           // 1,048,576 sh
  short* wpk3  = (short*)(ws + 3469056);           // 1,105,920 sh
  short* wpkK  = (short*)(ws + 4022016);           // 8,192 sh
  short* wpkV  = (short*)(ws + 4026112);           // 65,536 sh
  short* abf   = (short*)ws;                       // overlays pim+multi (dead by then)

  float* out  = (float*)d_out;
  float* attn = out + (size_t)BN * CC * NN;

  pad_kernel<<<dim3(37, 240), 256, 0, stream>>>(x0, x1, x2, x3, pim);

  repack_kernel<<<288, 256, 0, stream>>>(w0, wpk3, 32, 2, 73728);
  repack_kernel<<<576, 256, 0, stream>>>(w1, wpk3 + 73728, 64, 4, 147456);
  repack_kernel<<<1152, 256, 0, stream>>>(w2, wpk3 + 221184, 128, 8, 294912);
  repack_kernel<<<2304, 256, 0, stream>>>(w3, wpk3 + 516096, 256, 16, 589824);
  repack1x1_kernel<<<32, 256, 0, stream>>>(kw, wpkK, CC, 8192);
  repack1x1_kernel<<<256, 256, 0, stream>>>(vw, wpkV, CC, 65536);

  conv_mfma2_kernel<<<1024, 64, 0, stream>>>(pim, wpk3, s0, b0, s1, b1, s2, b2, s3, b3, multi);

  xT_kernel<<<1024, 256, 0, stream>>>(x, xT);

  mm1x1_kernel<<<32, 256, 0, stream>>>(multi, qw, qbi, qbuf, CC, DQ);

  proj1x1_kernel<<<128, 64, 0, stream>>>(wpkK, xT, kbi, relh, relw, kpbuf, nullptr, 1, DQ);
  proj1x1_kernel<<<1024, 64, 0, stream>>>(wpkV, xT, vbi, nullptr, nullptr, nullptr, vbf, 8, CC);

  attn_kernel<<<512, 256, 0, stream>>>(qbuf, kpbuf, attn, abf);

  out_mfma_kernel<<<256, 256, 0, stream>>>(vbf, abf, x, gamma, (float*)d_out);
}

// Round 6
// 107.766 us; speedup vs baseline: 12.9715x; 1.7569x over previous
//
#include <hip/hip_runtime.h>
#include <stdint.h>

#define BN 4
#define CC 256
#define DQ 32
#define HWD 32
#define NN 1024

typedef __attribute__((ext_vector_type(8))) short short8v;
typedef __attribute__((ext_vector_type(16))) float float16v;

// weight-pack element offsets
#define W3OFF0 0
#define W3OFF1 73728
#define W3OFF2 221184
#define W3OFF3 516096
#define WQOFF  1105920
#define WKOFF  1114112
#define WVOFF  1122304
#define WPKTOT 1187840

__device__ __forceinline__ short f2bf(float f) {
  union { float f; uint32_t u; } v; v.f = f;
  uint32_t r = v.u + 0x7FFFu + ((v.u >> 16) & 1u);
  return (short)(r >> 16);
}

// ---- fused downsample + pad + bf16 convert:  pim[b][g][34][34][8] ----------
__global__ __launch_bounds__(256) void pad_kernel(
    const float* __restrict__ x0, const float* __restrict__ x1,
    const float* __restrict__ x2, const float* __restrict__ x3,
    short* __restrict__ pim) {
  int plane = blockIdx.y;  // b*60+g
  int idx = blockIdx.x * 256 + threadIdx.x;
  if (idx >= 9248) return;
  int b = plane / 60, g = plane % 60;
  int pr = idx / 272;
  int rem = idx % 272;
  int pc = rem >> 3, j = rem & 7;
  const float* xs;
  int s, gb, C;
  if (g < 4)       { xs = x0; s = 16; gb = 0;  C = 32; }
  else if (g < 12) { xs = x1; s = 8;  gb = 4;  C = 64; }
  else if (g < 28) { xs = x2; s = 4;  gb = 12; C = 128; }
  else             { xs = x3; s = 2;  gb = 28; C = 256; }
  float v = 0.f;
  if (pr >= 1 && pr <= 32 && pc >= 1 && pc <= 32) {
    int c = (g - gb) * 8 + j;
    int inHW = 32 * s;
    int ih = (pr - 1) * s + (s >> 1) - 1;
    int iw = (pc - 1) * s + (s >> 1) - 1;
    const float* p = xs + ((size_t)(b * C + c) * inHW + ih) * inHW + iw;
    v = 0.25f * (p[0] + p[1] + p[inHW] + p[inHW + 1]);
  }
  pim[(size_t)plane * 9248 + idx] = f2bf(v);
}

// ---------------- unified weight repack (3x3 x4 scales + q/k/v 1x1) ---------
__global__ __launch_bounds__(256) void repack_all_kernel(
    const float* __restrict__ w0, const float* __restrict__ w1,
    const float* __restrict__ w2, const float* __restrict__ w3,
    const float* __restrict__ qw, const float* __restrict__ kw,
    const float* __restrict__ vw, short* __restrict__ wpk) {
  int idx = blockIdx.x * 256 + threadIdx.x;
  if (idx >= WPKTOT) return;
  const float* w;
  int Cin, chunks, taps, ridx;
  if (idx < W3OFF1)      { w = w0; Cin = 32;  chunks = 2;  taps = 9; ridx = idx; }
  else if (idx < W3OFF2) { w = w1; Cin = 64;  chunks = 4;  taps = 9; ridx = idx - W3OFF1; }
  else if (idx < W3OFF3) { w = w2; Cin = 128; chunks = 8;  taps = 9; ridx = idx - W3OFF2; }
  else if (idx < WQOFF)  { w = w3; Cin = 256; chunks = 16; taps = 9; ridx = idx - W3OFF3; }
  else if (idx < WKOFF)  { w = qw; Cin = 256; chunks = 16; taps = 1; ridx = idx - WQOFF; }
  else if (idx < WVOFF)  { w = kw; Cin = 256; chunks = 16; taps = 1; ridx = idx - WKOFF; }
  else                   { w = vw; Cin = 256; chunks = 16; taps = 1; ridx = idx - WVOFF; }
  int per = taps * 512;
  int g2 = ridx / per;
  int rem = ridx % per;
  int tap = rem >> 9;
  int l = (rem >> 3) & 63;
  int j = rem & 7;
  int ocg = g2 / chunks;
  int chunk = g2 % chunks;
  int oc = ocg * 32 + (l & 31);
  int c = chunk * 16 + ((l >> 5) << 3) + j;
  wpk[idx] = f2bf(w[((size_t)oc * Cin + c) * taps + tap]);
}

// ------- fused 4-scale conv3x3+BN+ReLU+sum -> multiT bf16 [b][c>>3][n][c&7] -
__global__ __launch_bounds__(64) void conv_mfma2_kernel(
    const short* __restrict__ pim, const short* __restrict__ wpk,
    const float* __restrict__ sc0, const float* __restrict__ bi0,
    const float* __restrict__ sc1, const float* __restrict__ bi1,
    const float* __restrict__ sc2, const float* __restrict__ bi2,
    const float* __restrict__ sc3, const float* __restrict__ bi3,
    short* __restrict__ multiT) {
  __shared__ float sT[32][33];
  int l = threadIdx.x;
  int bid = blockIdx.x;
  int row = bid & 31;
  int ocg = (bid >> 5) & 7;
  int b = bid >> 8;
  int col = l & 31, chH = l >> 5;
  int oc0 = ocg * 32;

  const float* scv[4] = {sc0, sc1, sc2, sc3};
  const float* biv[4] = {bi0, bi1, bi2, bi3};
  const int cins[4] = {32, 64, 128, 256};
  const int gbase[4] = {0, 4, 12, 28};
  const int wofs[4] = {W3OFF0, W3OFF1, W3OFF2, W3OFF3};

  float sum[16];
#pragma unroll
  for (int r = 0; r < 16; ++r) sum[r] = 0.f;

#pragma unroll
  for (int s = 0; s < 4; ++s) {
    int chunks = cins[s] >> 4;
    const short* ap = wpk + wofs[s] + (size_t)(ocg * chunks) * 4608 + l * 8;
    const short* bp = pim + ((size_t)(b * 60 + gbase[s] + chH) * 1156 + row * 34 + col) * 8;
    float16v acc;
#pragma unroll
    for (int r = 0; r < 16; ++r) acc[r] = 0.f;
    for (int ck = 0; ck < chunks; ++ck) {
#pragma unroll
      for (int ky = 0; ky < 3; ++ky)
#pragma unroll
        for (int kx = 0; kx < 3; ++kx) {
          short8v av = *(const short8v*)(ap + (ky * 3 + kx) * 512);
          short8v bv = *(const short8v*)(bp + (ky * 34 + kx) * 8);
          acc = __builtin_amdgcn_mfma_f32_32x32x16_bf16(av, bv, acc, 0, 0, 0);
        }
      ap += 4608;
      bp += 2 * 1156 * 8;
    }
    const float* sc = scv[s];
    const float* bi = biv[s];
#pragma unroll
    for (int r = 0; r < 16; ++r) {
      int ocl = (r & 3) + ((r >> 2) << 3) + (chH << 2);
      float t = fmaf(acc[r], sc[oc0 + ocl], bi[oc0 + ocl]);
      sum[r] += t > 0.f ? t : 0.f;
    }
  }
  // bounce through LDS to emit short8 chunks in multiT layout
#pragma unroll
  for (int r = 0; r < 16; ++r) {
    int ocl = (r & 3) + ((r >> 2) << 3) + (chH << 2);
    sT[ocl][col] = sum[r];
  }
  __syncthreads();
#pragma unroll
  for (int it = 0; it < 2; ++it) {
    int q = l + (it << 6);
    int c2 = q & 31;
    int cg = q >> 5;  // 0..3
    short8v o;
#pragma unroll
    for (int jj = 0; jj < 8; ++jj) o[jj] = f2bf(sT[cg * 8 + jj][c2]);
    *(short8v*)(multiT + (((size_t)(b * 32) + ocg * 4 + cg) * 1024 + row * 32 + c2) * 8) = o;
  }
}

// -------- transpose-convert x -> xT2 bf16 [b][c>>3][n][c&7] -----------------
__global__ __launch_bounds__(256) void xT2_kernel(const float* __restrict__ x,
                                                  short* __restrict__ xT2) {
  __shared__ float t[64][33];
  int bid = blockIdx.x;
  int nb = bid & 31;
  int cb = (bid >> 5) & 3;
  int b = bid >> 7;
  int n0 = nb * 32, c0 = cb * 64;
  int tid = threadIdx.x;
  int a = tid >> 5, e = tid & 31;
#pragma unroll
  for (int k = 0; k < 8; ++k)
    t[a + 8 * k][e] = x[((size_t)(b * CC + c0 + a + 8 * k) * NN) + n0 + e];
  __syncthreads();
  int n = tid & 31, cg = tid >> 5;  // cg 0..7
  short8v o;
#pragma unroll
  for (int jj = 0; jj < 8; ++jj) o[jj] = f2bf(t[cg * 8 + jj][n]);
  *(short8v*)(xT2 + (((size_t)(b * 32) + cb * 8 + cg) * 1024 + n0 + n) * 8) = o;
}

// -------- unified q/k/v 1x1 projections via MFMA ----------------------------
// bid 0..127: Q (multiT -> qbuf fp32) ; 128..255: K (+pos -> kpbuf fp32)
// bid 256..1279: V (-> vbf2 bf16 [b][n>>3][c][n&7])
__global__ __launch_bounds__(64) void proj_all_kernel(
    const short* __restrict__ multiT, const short* __restrict__ xT2,
    const short* __restrict__ wpk,
    const float* __restrict__ qbi, const float* __restrict__ kbi,
    const float* __restrict__ vbi,
    const float* __restrict__ relh, const float* __restrict__ relw,
    float* __restrict__ qbuf, float* __restrict__ kpbuf,
    short* __restrict__ vbf2) {
  int l = threadIdx.x;
  int bid = blockIdx.x;
  int mode, b, nt, ocg;
  const short* bsrc;
  const short* ap;
  const float* bias;
  if (bid < 128)      { mode = 0; b = bid >> 5; nt = bid & 31; ocg = 0; bsrc = multiT; ap = wpk + WQOFF; bias = qbi; }
  else if (bid < 256) { int t2 = bid - 128; mode = 1; b = t2 >> 5; nt = t2 & 31; ocg = 0; bsrc = xT2; ap = wpk + WKOFF; bias = kbi; }
  else                { int t2 = bid - 256; mode = 2; nt = t2 & 31; ocg = (t2 >> 5) & 7; b = t2 >> 8; bsrc = xT2; ap = wpk + WVOFF + (size_t)ocg * 16 * 512; bias = vbi; }
  int n = nt * 32 + (l & 31);
  int half = l >> 5;
  ap += l * 8;
  float16v acc;
#pragma unroll
  for (int r = 0; r < 16; ++r) acc[r] = 0.f;
#pragma unroll
  for (int ck = 0; ck < 16; ++ck) {
    short8v av = *(const short8v*)(ap + ck * 512);
    short8v bv = *(const short8v*)(bsrc + (((size_t)(b * 32) + ck * 2 + half) * 1024 + n) * 8);
    acc = __builtin_amdgcn_mfma_f32_32x32x16_bf16(av, bv, acc, 0, 0, 0);
  }
#pragma unroll
  for (int r = 0; r < 16; ++r) {
    int oc = ocg * 32 + (r & 3) + ((r >> 2) << 3) + (half << 2);
    float t = acc[r] + bias[oc];
    if (mode == 0) {
      qbuf[((size_t)b * DQ + oc) * NN + n] = t;
    } else if (mode == 1) {
      t += relh[oc * 32 + (n >> 5)] + relw[oc * 32 + (n & 31)];
      kpbuf[((size_t)b * DQ + oc) * NN + n] = t;
    } else {
      vbf2[(((size_t)(b * 128) + (n >> 3)) * 256 + oc) * 8 + (n & 7)] = f2bf(t);
    }
  }
}

// ---- energy = q·(k+pos), row softmax -> attn fp32 + abf2 bf16 [b][j>>3][i][j&7]
__global__ __launch_bounds__(256) void attn_kernel(
    const float* __restrict__ q, const float* __restrict__ kp,
    float* __restrict__ attn, short* __restrict__ abf2) {
  __shared__ float qs[DQ][8];
  __shared__ float redm[4][8], reds[4][8];
  int bidx = blockIdx.x;
  int ig = bidx & 127;
  int b = bidx >> 7;
  int i0 = ig * 8;
  int tid = threadIdx.x;
  if (tid < DQ * 8) {
    int c = tid >> 3, r = tid & 7;
    qs[c][r] = q[((size_t)b * DQ + c) * NN + i0 + r];
  }
  __syncthreads();
  float e[8][4];
#pragma unroll
  for (int r = 0; r < 8; ++r)
#pragma unroll
    for (int k = 0; k < 4; ++k) e[r][k] = 0.f;
  const float* kpb = kp + (size_t)b * DQ * NN + tid;
  for (int c = 0; c < DQ; ++c) {
    float k0 = kpb[0], k1 = kpb[256], k2 = kpb[512], k3 = kpb[768];
    kpb += NN;
#pragma unroll
    for (int r = 0; r < 8; ++r) {
      float qv = qs[c][r];
      e[r][0] = fmaf(qv, k0, e[r][0]);
      e[r][1] = fmaf(qv, k1, e[r][1]);
      e[r][2] = fmaf(qv, k2, e[r][2]);
      e[r][3] = fmaf(qv, k3, e[r][3]);
    }
  }
  int lane = tid & 63, wvi = tid >> 6;
#pragma unroll
  for (int r = 0; r < 8; ++r) {
    float mm = fmaxf(fmaxf(e[r][0], e[r][1]), fmaxf(e[r][2], e[r][3]));
#pragma unroll
    for (int off = 32; off > 0; off >>= 1) mm = fmaxf(mm, __shfl_xor(mm, off));
    if (lane == 0) redm[wvi][r] = mm;
  }
  __syncthreads();
#pragma unroll
  for (int r = 0; r < 8; ++r) {
    float mm = fmaxf(fmaxf(redm[0][r], redm[1][r]), fmaxf(redm[2][r], redm[3][r]));
    float ss = 0.f;
#pragma unroll
    for (int k = 0; k < 4; ++k) {
      e[r][k] = __expf(e[r][k] - mm);
      ss += e[r][k];
    }
#pragma unroll
    for (int off = 32; off > 0; off >>= 1) ss += __shfl_xor(ss, off);
    if (lane == 0) reds[wvi][r] = ss;
  }
  __syncthreads();
#pragma unroll
  for (int r = 0; r < 8; ++r) {
    float inv = 1.f / (reds[0][r] + reds[1][r] + reds[2][r] + reds[3][r]);
    int i = i0 + r;
    size_t base = ((size_t)b * NN + i) * NN + tid;
#pragma unroll
    for (int k = 0; k < 4; ++k) {
      int j = tid + k * 256;
      float a = e[r][k] * inv;
      attn[base + k * 256] = a;
      abf2[(((size_t)(b * 128) + (j >> 3)) * 1024 + i) * 8 + (j & 7)] = f2bf(a);
    }
  }
}

// ---- out = gamma * V . attn^T + x via MFMA, coalesced interleaved layouts --
__global__ __launch_bounds__(256) void out_mfma2_kernel(
    const short* __restrict__ vbf2, const short* __restrict__ abf2,
    const float* __restrict__ x, const float* __restrict__ gamma,
    float* __restrict__ out) {
  int tid = threadIdx.x;
  int l = tid & 63;
  int wv = tid >> 6;
  int wc = wv >> 1, wi = wv & 1;
  int bid = blockIdx.x;
  int ig = bid & 15;
  int cg = (bid >> 4) & 3;
  int b = bid >> 6;
  int c0 = cg * 64 + wc * 32;
  int i0 = ig * 64 + wi * 32;
  int half = l >> 5, lane31 = l & 31;

  const short* vbase = vbf2 + (size_t)b * 128 * 256 * 8 + ((size_t)half * 256 + c0 + lane31) * 8;
  const short* abase = abf2 + (size_t)b * 128 * 1024 * 8 + ((size_t)half * 1024 + i0 + lane31) * 8;

  float16v acc;
#pragma unroll
  for (int r = 0; r < 16; ++r) acc[r] = 0.f;

#pragma unroll 4
  for (int jc = 0; jc < 128; jc += 2) {
    short8v av = *(const short8v*)(vbase + (size_t)jc * 256 * 8);
    short8v bv = *(const short8v*)(abase + (size_t)jc * 1024 * 8);
    acc = __builtin_amdgcn_mfma_f32_32x32x16_bf16(av, bv, acc, 0, 0, 0);
  }

  float g = gamma[0];
  int i = i0 + lane31;
#pragma unroll
  for (int r = 0; r < 16; ++r) {
    int c = c0 + (r & 3) + ((r >> 2) << 3) + (half << 2);
    size_t off = ((size_t)b * CC + c) * NN + i;
    out[off] = fmaf(g, acc[r], x[off]);
  }
}

extern "C" void kernel_launch(void* const* d_in, const int* in_sizes, int n_in,
                              void* d_out, int out_size, void* d_ws, size_t ws_size,
                              hipStream_t stream) {
  const float* x    = (const float*)d_in[0];
  const float* x0   = (const float*)d_in[1];
  const float* x1   = (const float*)d_in[2];
  const float* x2   = (const float*)d_in[3];
  const float* x3   = (const float*)d_in[4];
  const float* w0   = (const float*)d_in[5];
  const float* s0   = (const float*)d_in[6];
  const float* b0   = (const float*)d_in[7];
  const float* w1   = (const float*)d_in[8];
  const float* s1   = (const float*)d_in[9];
  const float* b1   = (const float*)d_in[10];
  const float* w2   = (const float*)d_in[11];
  const float* s2   = (const float*)d_in[12];
  const float* b2   = (const float*)d_in[13];
  const float* w3   = (const float*)d_in[14];
  const float* s3   = (const float*)d_in[15];
  const float* b3   = (const float*)d_in[16];
  const float* qw   = (const float*)d_in[17];
  const float* qbi  = (const float*)d_in[18];
  const float* kw   = (const float*)d_in[19];
  const float* kbi  = (const float*)d_in[20];
  const float* vw   = (const float*)d_in[21];
  const float* vbi  = (const float*)d_in[22];
  const float* relh = (const float*)d_in[23];
  const float* relw = (const float*)d_in[24];
  const float* gamma= (const float*)d_in[25];

  float* ws = (float*)d_ws;
  short* pim    = (short*)ws;                 // 2,219,520 sh
  short* multiT = (short*)(ws + 1109760);     // 1,048,576 sh
  float* qbuf   = ws + 1634048;               // 131,072 f
  float* kpbuf  = ws + 1765120;               // 131,072 f
  short* xT2    = (short*)(ws + 1896192);     // 1,048,576 sh
  short* vbf2   = (short*)(ws + 2420480);     // 1,048,576 sh
  short* wpk    = (short*)(ws + 2944768);     // 1,187,840 sh
  short* abf2   = (short*)(ws + 3538688);     // 4,194,304 sh  (end 5,635,840 f)

  float* out  = (float*)d_out;
  float* attn = out + (size_t)BN * CC * NN;

  pad_kernel<<<dim3(37, 240), 256, 0, stream>>>(x0, x1, x2, x3, pim);

  repack_all_kernel<<<(WPKTOT + 255) / 256, 256, 0, stream>>>(w0, w1, w2, w3, qw, kw, vw, wpk);

  conv_mfma2_kernel<<<1024, 64, 0, stream>>>(pim, wpk, s0, b0, s1, b1, s2, b2, s3, b3, multiT);

  xT2_kernel<<<512, 256, 0, stream>>>(x, xT2);

  proj_all_kernel<<<1280, 64, 0, stream>>>(multiT, xT2, wpk, qbi, kbi, vbi,
                                           relh, relw, qbuf, kpbuf, vbf2);

  attn_kernel<<<512, 256, 0, stream>>>(qbuf, kpbuf, attn, abf2);

  out_mfma2_kernel<<<256, 256, 0, stream>>>(vbf2, abf2, x, gamma, out);
}